// Round 15
// baseline (331.567 us; speedup 1.0000x reference)
//
#include <hip/hip_runtime.h>

// FNO2d "kinet" forward. BS=2, H=W=24, WIDTH=20, M1=M2=12, N=576, NPAIR=165600.
// All f32. Output (2,24,24,1) flat = 1152 floats.
//
// Round-15: specp+fft_inv merged into ONE k_sconv per layer: each (b,o)
// block recomputes the full 20-channel spectrum IN-BLOCK (2 groups of 10
// channels, full-width parallel phases — unlike r10's serialized 2-channel
// iterations) and accumulates mode-mix in registers. FP sequence per output
// element is verbatim-identical to the split version -> bit-identical.
// 12 dispatches (was 16). Spatial-conv alternative rejected by arithmetic:
// LDS gather per MAC (~5.8cyc/wave) => ~60us/block.
//
// Ledger: runtime grid.sync ~39us (r9), acquire-spin barrier ~225us (r12),
// low-parallelism fusion +69us (r10), boundary ~5us (r13/r14 deltas) ->
// kernel boundaries are the cheapest grid-wide sync; 4x[sconv->pmax->vnew]
// chain is structurally irreducible (XCD L2 non-coherence).
//
// Collision algebra (verified round 2):
//   v_new[o] = v[o] + sum_q cmask[o,q] * [ (v[o]-v[q])/2 + vr[o,q]*R[c,q,o] ]
//   R[c,q,o] = +rv[pair(q,o)] if q<o, -rv[pair(o,q)] if q>o.

#define N_     576
#define NPAIR_ 165600
#define C_     20
#define NG     10     // channels per in-block spectrum group

// layer-0 transpose chunks (576-thread blocks): sconv0 431, pmax0 144
#define TR_SCONV_B 431
#define TR_PMAX_B  144
#define TRS0 0
#define TRP0 (TR_SCONV_B*576)   // 248256; +144*576=331200 == 2*NPAIR exactly

__device__ __forceinline__ float gelu_f(float x){
    return 0.5f * x * (1.0f + erff(x * 0.70710678118654752440f));
}

// transpose one pair-row: rv_init [b][c][pr] -> rvt [b][pr][20]
__device__ __forceinline__ void tr_one(const float* __restrict__ rvi,
                                       float* __restrict__ rvt, int t){
    if (t >= 2*NPAIR_) return;
    int bb = t / NPAIR_, pr = t % NPAIR_;
    size_t ibase = (size_t)bb*C_*NPAIR_ + pr;
    float v[C_];
    #pragma unroll
    for (int c=0;c<C_;c++) v[c] = rvi[ibase + (size_t)c*NPAIR_];
    float4* dst = (float4*)(rvt + (size_t)t*C_);
    #pragma unroll
    for (int q=0;q<5;q++) dst[q] = make_float4(v[4*q],v[4*q+1],v[4*q+2],v[4*q+3]);
}

// lift input row at (bb,hw) -> in[12]  (identical FP order throughout)
__device__ __forceinline__ void lift_in(const float* __restrict__ xin, int bb, int hw, float* in){
    int h = hw / 24, wc = hw % 24;
    const float* xp = xin + ((size_t)bb*N_ + hw)*10;
    #pragma unroll
    for (int q=0;q<10;q++) in[q] = xp[q];
    in[10] = (float)h  * (1.0f/23.0f);
    in[11] = (float)wc * (1.0f/23.0f);
}

// ==== fused spectral conv: blocks 0..39 = (b,o) full pipeline; 40..41 = p_t;
// ====                      42.. = layer-0 rv transpose chunk
__global__ void __launch_bounds__(576)
k_sconv(const float* __restrict__ x, const float* __restrict__ wr, const float* __restrict__ wi,
        const float* __restrict__ wk, const float* __restrict__ wb,
        float* __restrict__ p_t, float* __restrict__ a_t,
        const float* __restrict__ rvi, float* __restrict__ rvt,
        const float* __restrict__ xin, const float* __restrict__ fc0w,
        const float* __restrict__ fc0b, int layer0,
        unsigned* __restrict__ vmaxu){
    int bid = blockIdx.x;
    int tid = threadIdx.x;
    if (bid >= 42){                       // layer-0 only (grid=42 for layers >=1)
        tr_one(rvi, rvt, TRS0 + (bid-42)*576 + tid);
        return;
    }
    if (bid < 40){
        __shared__ float xg[NG*576];      // group channels; reused as X (r:0..2879, i:2880..5759)
        __shared__ float Tr[NG*288], Ti[NG*288];
        __shared__ float Fr[288], Fi[288], Yr[288], Yi[288];
        __shared__ float cst[24], snt[24];
        int bb = bid/20, o = bid%20;
        if (layer0 && bid == 0 && tid < 8) vmaxu[tid] = 0u;   // [4 layers][2 batches]
        if (tid < 24){
            float s, c;
            sincosf((float)tid * 0.26179938779914943654f, &s, &c);  // 2*pi/24
            cst[tid]=c; snt[tid]=s;
        }
        float fr = 0.f, fi2 = 0.f;        // mode-mix accumulators (tid<288)
        for (int g=0; g<2; ++g){
            __syncthreads();              // g=0: cst ready; g=1: xg/T reuse safe
            // phase 1: fill xg with channels g*NG .. g*NG+9
            if (layer0){
                for (int q=tid; q<NG*576; q+=576){
                    int cg=q/576, pos=q%576, c=g*NG+cg;
                    float in[12];
                    lift_in(xin, bb, pos, in);
                    float acc = fc0b[c];
                    #pragma unroll
                    for (int qq=0;qq<12;qq++) acc += in[qq]*fc0w[qq*C_+c];
                    xg[q] = acc;
                }
            } else {
                for (int q=tid; q<NG*576; q+=576){
                    int cg=q/576, pos=q%576, c=g*NG+cg;
                    xg[q] = x[(size_t)(bb*C_+c)*N_+pos];
                }
            }
            __syncthreads();
            // stage 1: along w   T[cg][h][ky]
            for (int q=tid; q<NG*288; q+=576){
                int cg=q/288, r=q%288, h=r/12, ky=r%12;
                float ar=0.f, ai=0.f;
                for (int w=0;w<24;w++){
                    int m = (ky*w) % 24;
                    float v = xg[cg*576 + h*24+w];
                    ar += v*cst[m];
                    ai -= v*snt[m];
                }
                Tr[q]=ar; Ti[q]=ai;
            }
            __syncthreads();
            // stage 2: along h   X[cg][kx][ky]  (into xg region)
            for (int q=tid; q<NG*288; q+=576){
                int cg=q/288, r=q%288, kx=r/12, ky=r%12;
                float ar=0.f, ai=0.f;
                for (int h=0;h<24;h++){
                    int m = (kx*h)%24;
                    float tr=Tr[cg*288 + h*12+ky], ti=Ti[cg*288 + h*12+ky];
                    float cc=cst[m], ss=snt[m];
                    ar += tr*cc + ti*ss;
                    ai += ti*cc - tr*ss;
                }
                xg[q]        = ar;        // Xr
                xg[NG*288+q] = ai;        // Xi
            }
            __syncthreads();
            // mode-mix partial: F += X_i * W_io for i in this group (order i=0..19 overall)
            if (tid < 288){
                int ky = tid%12, kx = tid/12;
                int half = (kx>=12) ? 1 : 0; int mx = kx - half*12;
                for (int ii=0; ii<NG; ++ii){
                    int i2 = g*NG + ii;
                    float xr  = xg[ii*288 + tid];
                    float xiv = xg[NG*288 + ii*288 + tid];
                    size_t widx = ((((size_t)half*20+i2)*20+o)*12+mx)*12+ky;
                    float wrv = wr[widx], wiv = wi[widx];
                    fr  += xr*wrv - xiv*wiv;
                    fi2 += xr*wiv + xiv*wrv;
                }
            }
        }
        if (tid < 288){ Fr[tid]=fr; Fi[tid]=fi2; }
        __syncthreads();
        if (tid < 288){  // ifft along kx
            int h = tid/12;
            float ar=0.f, ai=0.f;
            for (int kx=0;kx<24;kx++){
                int m=(kx*h)%24;
                float frv=Fr[kx*12 + (tid%12)], fiv=Fi[kx*12 + (tid%12)];
                ar += frv*cst[m] - fiv*snt[m];
                ai += frv*snt[m] + fiv*cst[m];
            }
            Yr[tid]=ar*(1.0f/24.0f); Yi[tid]=ai*(1.0f/24.0f);
        }
        __syncthreads();
        {   // irfft along ky (imag of ky=0 discarded by irfft)
            int h = tid/24, w = tid%24;
            float acc = Yr[h*12+0];
            #pragma unroll
            for (int ky=1;ky<12;ky++){
                int m=(ky*w)%24;
                acc += 2.0f*(Yr[h*12+ky]*cst[m] - Yi[h*12+ky]*snt[m]);
            }
            a_t[((size_t)bb*N_ + tid)*C_ + o] = acc*(1.0f/24.0f);
        }
    } else {
        // p_t blocks (bid 40,41): 1152 positions over 2x576 threads
        __shared__ float swk[400], swb[C_];
        for (int q=tid;q<400;q+=576) swk[q]=wk[q];
        if (tid < C_) swb[tid]=wb[tid];
        __syncthreads();
        int t = (bid-40)*576 + tid;            // (b,hw) < 1152
        if (t >= 2*N_) return;
        int bb = t / N_, hw = t % N_;
        float xi[C_];
        if (layer0){
            float in[12];
            lift_in(xin, bb, hw, in);
            #pragma unroll
            for (int c=0;c<C_;c++){
                float acc = fc0b[c];
                #pragma unroll
                for (int qq=0;qq<12;qq++) acc += in[qq]*fc0w[qq*C_+c];
                xi[c] = acc;
            }
        } else {
            #pragma unroll
            for (int c=0;c<C_;c++) xi[c] = x[(size_t)(bb*C_+c)*N_+hw];
        }
        float accv[C_];
        #pragma unroll
        for (int o=0;o<C_;o++){
            float acc = swb[o];
            #pragma unroll
            for (int c=0;c<C_;c++) acc += xi[c]*swk[o*C_+c];
            accv[o]=acc;
        }
        float4* dst = (float4*)(p_t + (size_t)t*C_);
        #pragma unroll
        for (int q=0;q<5;q++) dst[q] = make_float4(accv[4*q],accv[4*q+1],accv[4*q+2],accv[4*q+3]);
    }
}

// ---- v_r global max (blocks 0..1151) + layer-0 transpose (1152..) ----
__global__ void k_pairmax(const float* __restrict__ a_t, float* __restrict__ vmax,
                          const float* __restrict__ rvi, float* __restrict__ rvt){
    if (blockIdx.x >= 2*N_){
        tr_one(rvi, rvt, TRP0 + (blockIdx.x-2*N_)*576 + (int)threadIdx.x);
        return;
    }
    __shared__ float ai[C_], wred[9];
    int bb = blockIdx.x/N_, i = blockIdx.x%N_;
    int j = threadIdx.x;                         // 576 threads
    if (j < C_) ai[j]=a_t[((size_t)bb*N_+i)*C_+j];
    __syncthreads();
    const float4* aj4 = (const float4*)(a_t + ((size_t)bb*N_+j)*C_);
    float ssv=0.f;
    #pragma unroll
    for (int q=0;q<5;q++){
        float4 av = aj4[q];
        float dv;
        dv = ai[4*q+0]-av.x; ssv += dv*dv;
        dv = ai[4*q+1]-av.y; ssv += dv*dv;
        dv = ai[4*q+2]-av.z; ssv += dv*dv;
        dv = ai[4*q+3]-av.w; ssv += dv*dv;
    }
    // max over ssv, one sqrt at the end: bit-identical (sqrt monotone)
    float m = ssv;
    #pragma unroll
    for (int off=32; off; off>>=1) m = fmaxf(m, __shfl_down(m, off, 64));
    if ((j&63)==0) wred[j>>6] = m;
    __syncthreads();
    if (j==0){
        float mm = wred[0];
        #pragma unroll
        for (int q=1;q<9;q++) mm = fmaxf(mm, wred[q]);
        atomicMax((unsigned int*)&vmax[bb], __float_as_uint(sqrtf(mm+1e-12f)));   // v_r >= 0
    }
}

// -------- collision update (+ fused output head on the last layer) --------
__global__ void __launch_bounds__(256, 1)
k_vnew(const float* __restrict__ p_t, const float* __restrict__ a_t,
       const float* __restrict__ rvt, const float* __restrict__ vmax,
       const float* __restrict__ rs, int klayer,
       float* __restrict__ xout, int do_head,
       const float* __restrict__ fc1w, const float* __restrict__ fc1b,
       const float* __restrict__ fc2w, const float* __restrict__ fc2b,
       float* __restrict__ out){
    __shared__ float pi[C_], ai[C_];
    __shared__ short hlist[N_];
    __shared__ int cnts[4];
    __shared__ float wacc[4][C_];
    __shared__ float xrow[C_];
    __shared__ float psum[2];
    int bb = blockIdx.x/N_, i = blockIdx.x%N_;
    int tid = threadIdx.x;
    int wid = tid>>6, lane = tid&63;
    if (tid < C_){ pi[tid]=p_t[((size_t)bb*N_+i)*C_+tid]; ai[tid]=a_t[((size_t)bb*N_+i)*C_+tid]; }
    __syncthreads();
    float vm = vmax[bb];
    const float thr = 0.1f;                      // f32(1.0 - 0.9), JAX weak-type
    const float4* pbase = (const float4*)(p_t + (size_t)bb*N_*C_);
    const float4* abase = (const float4*)(a_t + (size_t)bb*N_*C_);

    int jb = wid*144;
    unsigned long long m0, m1, m2;
    {
        auto test = [&](int j)->bool{
            const float4* pj = pbase + j*5;
            const float4* aj = abase + j*5;
            float ssx=0.f, ssv=0.f;
            #pragma unroll
            for (int q=0;q<5;q++){
                float4 pv = pj[q], av = aj[q];
                float dx, dv;
                dx = pi[4*q+0]-pv.x; dv = ai[4*q+0]-av.x; ssx += dx*dx; ssv += dv*dv;
                dx = pi[4*q+1]-pv.y; dv = ai[4*q+1]-av.y; ssx += dx*dx; ssv += dv*dv;
                dx = pi[4*q+2]-pv.z; dv = ai[4*q+2]-av.z; ssx += dx*dx; ssv += dv*dv;
                dx = pi[4*q+3]-pv.w; dv = ai[4*q+3]-av.w; ssx += dx*dx; ssv += dv*dv;
            }
            float vrv = sqrtf(ssv+1e-12f);
            float uxv = expf(-sqrtf(ssx+1e-12f));
            return ((vrv/vm)*uxv > thr) && (j != i);
        };
        int j = jb + lane;
        m0 = __ballot(test(j));
        m1 = __ballot(test(j+64));
        bool h2 = (lane<16) ? test(jb+128+lane) : false;
        m2 = __ballot(h2);
    }
    if (lane == 0) cnts[wid] = (int)(__popcll(m0)+__popcll(m1)+__popcll(m2));
    __syncthreads();
    int off = 0;
    #pragma unroll
    for (int w=0;w<4;w++) if (w < wid) off += cnts[w];
    int nhit = cnts[0]+cnts[1]+cnts[2]+cnts[3];
    {
        unsigned long long below = (1ULL<<lane)-1ULL;
        int base = off;
        if (m0 & (1ULL<<lane)) hlist[base + __popcll(m0 & below)] = (short)(jb + lane);
        base += (int)__popcll(m0);
        if (m1 & (1ULL<<lane)) hlist[base + __popcll(m1 & below)] = (short)(jb + 64 + lane);
        base += (int)__popcll(m1);
        if (m2 & (1ULL<<lane)) hlist[base + __popcll(m2 & below)] = (short)(jb + 128 + lane);
    }
    __syncthreads();

    float s_arr[4] = { rs[0], rs[1], rs[2], rs[3] };
    float macc[C_];                              // = rA - 0.5*sum(a_q)
    #pragma unroll
    for (int c=0;c<C_;c++) macc[c]=0.f;

    for (int t=tid; t<nhit; t+=256){
        int j = hlist[t];
        float av[C_];
        {
            const float4* aj = abase + j*5;
            #pragma unroll
            for (int q=0;q<5;q++){
                float4 aa = aj[q];
                av[4*q+0]=aa.x; av[4*q+1]=aa.y; av[4*q+2]=aa.z; av[4*q+3]=aa.w;
            }
        }
        float ssv=0.f;
        #pragma unroll
        for (int c=0;c<C_;c++){ float dv = ai[c]-av[c]; ssv += dv*dv; }
        float vrij = sqrtf(ssv+1e-12f);
        float sgn = (j<i) ? 1.0f : -1.0f;        // R[c,j,i] sign
        int lo = (j<i)?j:i, hi = (j<i)?i:j;
        int pidx = lo*(2*N_-lo-1)/2 + (hi-lo-1);
        float vrs = sgn*vrij;
        float st[C_];
        {
            const float4* rp = (const float4*)(rvt + ((size_t)bb*NPAIR_ + pidx)*C_);
            #pragma unroll
            for (int q=0;q<5;q++){
                float4 rr = rp[q];
                st[4*q+0]=rr.x; st[4*q+1]=rr.y; st[4*q+2]=rr.z; st[4*q+3]=rr.w;
            }
        }
        float ssq = 0.f;
        #pragma unroll
        for (int c=0;c<C_;c++) ssq += st[c]*st[c];
        float ini = 1.0f/sqrtf(ssq);
        float orc[C_];
        #pragma unroll
        for (int c=0;c<C_;c++) orc[c] = st[c]*ini;
        for (int l=0; l<=klayer; l++){
            float s = s_arr[l];
            float nq = 0.f;
            #pragma unroll
            for (int c=0;c<C_;c++){
                float nv = st[c]*orc[c] + orc[c] + s;
                st[c] = nv; nq += nv*nv;
            }
            float inn = 1.0f/sqrtf(nq);
            #pragma unroll
            for (int c=0;c<C_;c++) st[c] *= inn;
        }
        #pragma unroll
        for (int c=0;c<C_;c++) macc[c] += vrs*st[c] - 0.5f*av[c];
    }
    #pragma unroll
    for (int off2=32; off2; off2>>=1){
        #pragma unroll
        for (int c=0;c<C_;c++) macc[c] += __shfl_xor(macc[c], off2, 64);
    }
    if (lane == 0){
        #pragma unroll
        for (int c=0;c<C_;c++) wacc[wid][c] = macc[c];
    }
    __syncthreads();
    if (!do_head){
        if (tid < C_){
            int c = tid;
            float msum = wacc[0][c]+wacc[1][c]+wacc[2][c]+wacc[3][c];
            float vi = ai[c];
            float vnew = vi + 0.5f*(float)nhit*vi + msum;
            float xn = pi[c] + vnew;
            xout[(size_t)(bb*C_+c)*N_+i] = gelu_f(xn);   // channel-major for next layer
        }
    } else {
        if (tid < C_){
            int c = tid;
            float msum = wacc[0][c]+wacc[1][c]+wacc[2][c]+wacc[3][c];
            float vi = ai[c];
            float vnew = vi + 0.5f*(float)nhit*vi + msum;
            xrow[c] = pi[c] + vnew;                      // layer 3: no gelu
        }
        __syncthreads();
        if (tid < 128){
            float h = fc1b[tid];
            #pragma unroll
            for (int c=0;c<C_;c++) h += xrow[c]*fc1w[c*128+tid];
            float g = gelu_f(h)*fc2w[tid];
            #pragma unroll
            for (int off2=32; off2; off2>>=1) g += __shfl_down(g, off2, 64);
            if (lane==0) psum[wid] = g;
        }
        __syncthreads();
        if (tid==0) out[bb*N_+i] = psum[0] + psum[1] + fc2b[0];
    }
}

extern "C" void kernel_launch(void* const* d_in, const int* in_sizes, int n_in,
                              void* d_out, int out_size, void* d_ws, size_t ws_size,
                              hipStream_t stream) {
    const float* in_x   = (const float*)d_in[0];
    // d_in[1] (v) is dead in the reference forward
    const float* fc0_w  = (const float*)d_in[2];
    const float* fc0_b  = (const float*)d_in[3];
    const float* sc_wr  = (const float*)d_in[4];
    const float* sc_wi  = (const float*)d_in[5];
    const float* w_k    = (const float*)d_in[6];
    const float* w_b    = (const float*)d_in[7];
    const float* fc1_w  = (const float*)d_in[8];
    const float* fc1_b  = (const float*)d_in[9];
    const float* fc2_w  = (const float*)d_in[10];
    const float* fc2_b  = (const float*)d_in[11];
    const float* rv_init= (const float*)d_in[12];
    const float* rv_s   = (const float*)d_in[13];
    float* out = (float*)d_out;
    float* ws  = (float*)d_ws;

    // workspace layout (floats); total 6,693,128 floats = 26.8 MB
    float* rvt   = ws;                 // 6,624,000  [b][pair][20]
    float* x_cur = ws + 6624000;       // 23040      [b][c][n]
    float* p_t   = ws + 6647040;       // 23040      [b][n][20]
    float* a_t   = ws + 6670080;       // 23040      [b][n][20]
    float* vmax  = ws + 6693120;       // 8 = [4 layers][2 batches]

    for (int k=0;k<4;k++){
        const size_t woff = (size_t)k*115200;  // 2*20*20*144
        int g_sc = (k==0) ? 42 + TR_SCONV_B : 42;
        int g_pm = (k==0) ? 2*N_ + TR_PMAX_B : 2*N_;
        k_sconv<<<g_sc, 576, 0, stream>>>(x_cur, sc_wr+woff, sc_wi+woff,
                                          w_k + k*400, w_b + k*20, p_t, a_t,
                                          rv_init, rvt, in_x, fc0_w, fc0_b,
                                          (k==0) ? 1 : 0, (unsigned*)vmax);
        k_pairmax<<<g_pm, N_, 0, stream>>>(a_t, vmax + 2*k, rv_init, rvt);
        k_vnew<<<2*N_, 256, 0, stream>>>(p_t, a_t, rvt, vmax + 2*k, rv_s, k,
                                         x_cur, (k==3) ? 1 : 0,
                                         fc1_w, fc1_b, fc2_w, fc2_b, out);
    }
}

// Round 16
// 209.262 us; speedup vs baseline: 1.5845x; 1.5845x over previous
//
#include <hip/hip_runtime.h>

// FNO2d "kinet" forward. BS=2, H=W=24, WIDTH=20, M1=M2=12, N=576, NPAIR=165600.
// All f32. Output (2,24,24,1) flat = 1152 floats.
//
// Round-16: verbatim revert to round 14 (209.87us, best). Round-15's
// in-block 20-channel spectral fusion hit the 576-thread VGPR cap (48 regs,
// ~90 live) -> scratch spills (WRITE 20MB vs 185KB output) + 51.5KB LDS:
// 53us/dispatch. Ledger of measured dead ends on gfx950:
//   - runtime grid.sync ~39us each (r9)
//   - acquire-spin in-kernel barrier ~225us (r12: agent-acquire = L2-inv storm)
//   - low-parallelism fusion +69us (r10); VGPR-capped wide-block fusion +120us (r15)
//   - kernel boundary ~5us (r13/r14 single-dispatch deltas)
// => 16 small dispatches with per-layer split is the measured optimum;
//    chain 4x[specp->inv->pmax->vnew] irreducible (XCD L2 non-coherence).
//
// Collision algebra (verified round 2):
//   v_new[o] = v[o] + sum_q cmask[o,q] * [ (v[o]-v[q])/2 + vr[o,q]*R[c,q,o] ]
//   R[c,q,o] = +rv[pair(q,o)] if q<o, -rv[pair(o,q)] if q>o.

#define N_     576
#define NPAIR_ 165600
#define C_     20

// transpose chunk starts (pair rows): specp0 512x288, inv0 192x576, pmax0 144x576
#define TR_SPEC_B 512
#define TR_INV_B  192
#define TR_PMAX_B 144
#define TRS0 0
#define TRI0 (TR_SPEC_B*288)          // 147456
#define TRP0 (TRI0 + TR_INV_B*576)    // 258048 (+144*576=340992 >= 331200)

__device__ __forceinline__ float gelu_f(float x){
    return 0.5f * x * (1.0f + erff(x * 0.70710678118654752440f));
}

// transpose one pair-row: rv_init [b][c][pr] -> rvt [b][pr][20]
__device__ __forceinline__ void tr_one(const float* __restrict__ rvi,
                                       float* __restrict__ rvt, int t){
    if (t >= 2*NPAIR_) return;
    int bb = t / NPAIR_, pr = t % NPAIR_;
    size_t ibase = (size_t)bb*C_*NPAIR_ + pr;
    float v[C_];
    #pragma unroll
    for (int c=0;c<C_;c++) v[c] = rvi[ibase + (size_t)c*NPAIR_];
    float4* dst = (float4*)(rvt + (size_t)t*C_);
    #pragma unroll
    for (int q=0;q<5;q++) dst[q] = make_float4(v[4*q],v[4*q+1],v[4*q+2],v[4*q+3]);
}

// lift input row at (bb,hw) -> in[12]  (identical FP order to original k_lift)
__device__ __forceinline__ void lift_in(const float* __restrict__ xin, int bb, int hw, float* in){
    int h = hw / 24, wc = hw % 24;
    const float* xp = xin + ((size_t)bb*N_ + hw)*10;
    #pragma unroll
    for (int q=0;q<10;q++) in[q] = xp[q];
    in[10] = (float)h  * (1.0f/23.0f);
    in[11] = (float)wc * (1.0f/23.0f);
}

// ---- fwd DFT (blocks 0..39 per (b,c)) + p_t (blocks 40..43) + transpose (44..) ----
// layer0: lift recomputed inline from xin (x_cur not yet written).
__global__ void k_specp(const float* __restrict__ x, float* __restrict__ Xr, float* __restrict__ Xi,
                        const float* __restrict__ wk, const float* __restrict__ wb,
                        float* __restrict__ p_t,
                        const float* __restrict__ rvi, float* __restrict__ rvt,
                        const float* __restrict__ xin, const float* __restrict__ fc0w,
                        const float* __restrict__ fc0b, int layer0,
                        unsigned* __restrict__ vmaxu){
    if (blockIdx.x >= 44){
        tr_one(rvi, rvt, TRS0 + (blockIdx.x-44)*288 + (int)threadIdx.x);
        return;
    }
    if (blockIdx.x < 40){
        __shared__ float xt[576], Tr[288], Ti[288], cst[24], snt[24];
        int bc = blockIdx.x;           // b*20+c
        int tid = threadIdx.x;         // 288 threads
        if (layer0 && bc == 0 && tid < 8) vmaxu[tid] = 0u;   // [4 layers][2 batches]
        if (tid < 24){
            float s, c;
            sincosf((float)tid * 0.26179938779914943654f, &s, &c);  // 2*pi/24
            cst[tid]=c; snt[tid]=s;
        }
        if (layer0){
            int bb = bc/20, c = bc%20;
            for (int q=tid;q<576;q+=288){
                float in[12];
                lift_in(xin, bb, q, in);
                float acc = fc0b[c];
                #pragma unroll
                for (int qq=0;qq<12;qq++) acc += in[qq]*fc0w[qq*C_+c];
                xt[q] = acc;
            }
        } else {
            for (int q=tid;q<576;q+=288) xt[q] = x[(size_t)bc*576+q];
        }
        __syncthreads();
        {   // stage 1: along w
            int h = tid/12, ky = tid%12;
            float ar=0.f, ai=0.f;
            for (int w=0;w<24;w++){
                int m = (ky*w) % 24;
                float v = xt[h*24+w];
                ar += v*cst[m];
                ai -= v*snt[m];
            }
            Tr[tid]=ar; Ti[tid]=ai;
        }
        __syncthreads();
        {   // stage 2: along h
            int kx = tid/12, ky = tid%12;
            float ar=0.f, ai=0.f;
            for (int h=0;h<24;h++){
                int m = (kx*h)%24;
                float tr=Tr[h*12+ky], ti=Ti[h*12+ky];
                float cc=cst[m], ss=snt[m];
                ar += tr*cc + ti*ss;
                ai += ti*cc - tr*ss;
            }
            Xr[(size_t)bc*288 + tid] = ar;
            Xi[(size_t)bc*288 + tid] = ai;
        }
    } else {
        __shared__ float swk[400], swb[C_];
        int tid = threadIdx.x;
        for (int q=tid;q<400;q+=288) swk[q]=wk[q];
        if (tid < C_) swb[tid]=wb[tid];
        __syncthreads();
        int t = (blockIdx.x-40)*288 + tid;            // (b,hw) < 1152
        if (t >= 2*N_) return;
        int bb = t / N_, hw = t % N_;
        float xi[C_];
        if (layer0){
            float in[12];
            lift_in(xin, bb, hw, in);
            #pragma unroll
            for (int c=0;c<C_;c++){
                float acc = fc0b[c];
                #pragma unroll
                for (int qq=0;qq<12;qq++) acc += in[qq]*fc0w[qq*C_+c];
                xi[c] = acc;
            }
        } else {
            #pragma unroll
            for (int c=0;c<C_;c++) xi[c] = x[(size_t)(bb*C_+c)*N_+hw];
        }
        float accv[C_];
        #pragma unroll
        for (int o=0;o<C_;o++){
            float acc = swb[o];
            #pragma unroll
            for (int c=0;c<C_;c++) acc += xi[c]*swk[o*C_+c];
            accv[o]=acc;
        }
        float4* dst = (float4*)(p_t + (size_t)t*C_);
        #pragma unroll
        for (int q=0;q<5;q++) dst[q] = make_float4(accv[4*q],accv[4*q+1],accv[4*q+2],accv[4*q+3]);
    }
}

// ---- mode-mix + inverse FFT (blocks 0..39 per (b,o)) + transpose (40..) ----
__global__ void k_fft_inv(const float* __restrict__ Xr, const float* __restrict__ Xi,
                          const float* __restrict__ wr, const float* __restrict__ wi,
                          float* __restrict__ a_t,
                          const float* __restrict__ rvi, float* __restrict__ rvt){
    if (blockIdx.x >= 40){
        tr_one(rvi, rvt, TRI0 + (blockIdx.x-40)*576 + (int)threadIdx.x);
        return;
    }
    __shared__ float Fr[288], Fi[288], Yr[288], Yi[288], cst[24], snt[24];
    int bo = blockIdx.x; int bb = bo/20, o = bo%20;
    int tid = threadIdx.x;    // 576 threads
    if (tid < 24){
        float s, c;
        sincosf((float)tid * 0.26179938779914943654f, &s, &c);
        cst[tid]=c; snt[tid]=s;
    }
    if (tid < 288){   // mode mixing: F[kx][ky] = sum_i X[b,i,kx,ky]*W[i,o,...]
        int ky = tid%12, kx = tid/12;
        int half = (kx>=12) ? 1 : 0; int mx = kx - half*12;
        float ar=0.f, ai=0.f;
        for (int i=0;i<20;i++){
            float xr = Xr[(size_t)(bb*20+i)*288 + tid];
            float xi = Xi[(size_t)(bb*20+i)*288 + tid];
            size_t widx = ((((size_t)half*20+i)*20+o)*12+mx)*12+ky;
            float wrv = wr[widx], wiv = wi[widx];
            ar += xr*wrv - xi*wiv;
            ai += xr*wiv + xi*wrv;
        }
        Fr[tid]=ar; Fi[tid]=ai;
    }
    __syncthreads();
    if (tid < 288){  // ifft along kx
        int h = tid/12;
        float ar=0.f, ai=0.f;
        for (int kx=0;kx<24;kx++){
            int m=(kx*h)%24;
            float fr=Fr[kx*12 + (tid%12)], fi=Fi[kx*12 + (tid%12)];
            ar += fr*cst[m] - fi*snt[m];
            ai += fr*snt[m] + fi*cst[m];
        }
        Yr[tid]=ar*(1.0f/24.0f); Yi[tid]=ai*(1.0f/24.0f);
    }
    __syncthreads();
    {   // irfft along ky (imag of ky=0 discarded by irfft)
        int h = tid/24, w = tid%24;
        float acc = Yr[h*12+0];
        #pragma unroll
        for (int ky=1;ky<12;ky++){
            int m=(ky*w)%24;
            acc += 2.0f*(Yr[h*12+ky]*cst[m] - Yi[h*12+ky]*snt[m]);
        }
        a_t[((size_t)bb*N_ + tid)*C_ + o] = acc*(1.0f/24.0f);
    }
}

// ---- v_r global max (blocks 0..1151) + transpose (1152..) ----
__global__ void k_pairmax(const float* __restrict__ a_t, float* __restrict__ vmax,
                          const float* __restrict__ rvi, float* __restrict__ rvt){
    if (blockIdx.x >= 2*N_){
        tr_one(rvi, rvt, TRP0 + (blockIdx.x-2*N_)*576 + (int)threadIdx.x);
        return;
    }
    __shared__ float ai[C_], wred[9];
    int bb = blockIdx.x/N_, i = blockIdx.x%N_;
    int j = threadIdx.x;                         // 576 threads
    if (j < C_) ai[j]=a_t[((size_t)bb*N_+i)*C_+j];
    __syncthreads();
    const float4* aj4 = (const float4*)(a_t + ((size_t)bb*N_+j)*C_);
    float ssv=0.f;
    #pragma unroll
    for (int q=0;q<5;q++){
        float4 av = aj4[q];
        float dv;
        dv = ai[4*q+0]-av.x; ssv += dv*dv;
        dv = ai[4*q+1]-av.y; ssv += dv*dv;
        dv = ai[4*q+2]-av.z; ssv += dv*dv;
        dv = ai[4*q+3]-av.w; ssv += dv*dv;
    }
    // max over ssv, one sqrt at the end: bit-identical (sqrt monotone)
    float m = ssv;
    #pragma unroll
    for (int off=32; off; off>>=1) m = fmaxf(m, __shfl_down(m, off, 64));
    if ((j&63)==0) wred[j>>6] = m;
    __syncthreads();
    if (j==0){
        float mm = wred[0];
        #pragma unroll
        for (int q=1;q<9;q++) mm = fmaxf(mm, wred[q]);
        atomicMax((unsigned int*)&vmax[bb], __float_as_uint(sqrtf(mm+1e-12f)));   // v_r >= 0
    }
}

// -------- collision update (+ fused output head on the last layer) --------
__global__ void __launch_bounds__(256, 1)
k_vnew(const float* __restrict__ p_t, const float* __restrict__ a_t,
       const float* __restrict__ rvt, const float* __restrict__ vmax,
       const float* __restrict__ rs, int klayer,
       float* __restrict__ xout, int do_head,
       const float* __restrict__ fc1w, const float* __restrict__ fc1b,
       const float* __restrict__ fc2w, const float* __restrict__ fc2b,
       float* __restrict__ out){
    __shared__ float pi[C_], ai[C_];
    __shared__ short hlist[N_];
    __shared__ int cnts[4];
    __shared__ float wacc[4][C_];
    __shared__ float xrow[C_];
    __shared__ float psum[2];
    int bb = blockIdx.x/N_, i = blockIdx.x%N_;
    int tid = threadIdx.x;
    int wid = tid>>6, lane = tid&63;
    if (tid < C_){ pi[tid]=p_t[((size_t)bb*N_+i)*C_+tid]; ai[tid]=a_t[((size_t)bb*N_+i)*C_+tid]; }
    __syncthreads();
    float vm = vmax[bb];
    const float thr = 0.1f;                      // f32(1.0 - 0.9), JAX weak-type
    const float4* pbase = (const float4*)(p_t + (size_t)bb*N_*C_);
    const float4* abase = (const float4*)(a_t + (size_t)bb*N_*C_);

    int jb = wid*144;
    unsigned long long m0, m1, m2;
    {
        auto test = [&](int j)->bool{
            const float4* pj = pbase + j*5;
            const float4* aj = abase + j*5;
            float ssx=0.f, ssv=0.f;
            #pragma unroll
            for (int q=0;q<5;q++){
                float4 pv = pj[q], av = aj[q];
                float dx, dv;
                dx = pi[4*q+0]-pv.x; dv = ai[4*q+0]-av.x; ssx += dx*dx; ssv += dv*dv;
                dx = pi[4*q+1]-pv.y; dv = ai[4*q+1]-av.y; ssx += dx*dx; ssv += dv*dv;
                dx = pi[4*q+2]-pv.z; dv = ai[4*q+2]-av.z; ssx += dx*dx; ssv += dv*dv;
                dx = pi[4*q+3]-pv.w; dv = ai[4*q+3]-av.w; ssx += dx*dx; ssv += dv*dv;
            }
            float vrv = sqrtf(ssv+1e-12f);
            float uxv = expf(-sqrtf(ssx+1e-12f));
            return ((vrv/vm)*uxv > thr) && (j != i);
        };
        int j = jb + lane;
        m0 = __ballot(test(j));
        m1 = __ballot(test(j+64));
        bool h2 = (lane<16) ? test(jb+128+lane) : false;
        m2 = __ballot(h2);
    }
    if (lane == 0) cnts[wid] = (int)(__popcll(m0)+__popcll(m1)+__popcll(m2));
    __syncthreads();
    int off = 0;
    #pragma unroll
    for (int w=0;w<4;w++) if (w < wid) off += cnts[w];
    int nhit = cnts[0]+cnts[1]+cnts[2]+cnts[3];
    {
        unsigned long long below = (1ULL<<lane)-1ULL;
        int base = off;
        if (m0 & (1ULL<<lane)) hlist[base + __popcll(m0 & below)] = (short)(jb + lane);
        base += (int)__popcll(m0);
        if (m1 & (1ULL<<lane)) hlist[base + __popcll(m1 & below)] = (short)(jb + 64 + lane);
        base += (int)__popcll(m1);
        if (m2 & (1ULL<<lane)) hlist[base + __popcll(m2 & below)] = (short)(jb + 128 + lane);
    }
    __syncthreads();

    float s_arr[4] = { rs[0], rs[1], rs[2], rs[3] };
    float macc[C_];                              // = rA - 0.5*sum(a_q)
    #pragma unroll
    for (int c=0;c<C_;c++) macc[c]=0.f;

    for (int t=tid; t<nhit; t+=256){
        int j = hlist[t];
        float av[C_];
        {
            const float4* aj = abase + j*5;
            #pragma unroll
            for (int q=0;q<5;q++){
                float4 aa = aj[q];
                av[4*q+0]=aa.x; av[4*q+1]=aa.y; av[4*q+2]=aa.z; av[4*q+3]=aa.w;
            }
        }
        float ssv=0.f;
        #pragma unroll
        for (int c=0;c<C_;c++){ float dv = ai[c]-av[c]; ssv += dv*dv; }
        float vrij = sqrtf(ssv+1e-12f);
        float sgn = (j<i) ? 1.0f : -1.0f;        // R[c,j,i] sign
        int lo = (j<i)?j:i, hi = (j<i)?i:j;
        int pidx = lo*(2*N_-lo-1)/2 + (hi-lo-1);
        float vrs = sgn*vrij;
        float st[C_];
        {
            const float4* rp = (const float4*)(rvt + ((size_t)bb*NPAIR_ + pidx)*C_);
            #pragma unroll
            for (int q=0;q<5;q++){
                float4 rr = rp[q];
                st[4*q+0]=rr.x; st[4*q+1]=rr.y; st[4*q+2]=rr.z; st[4*q+3]=rr.w;
            }
        }
        float ssq = 0.f;
        #pragma unroll
        for (int c=0;c<C_;c++) ssq += st[c]*st[c];
        float ini = 1.0f/sqrtf(ssq);
        float orc[C_];
        #pragma unroll
        for (int c=0;c<C_;c++) orc[c] = st[c]*ini;
        for (int l=0; l<=klayer; l++){
            float s = s_arr[l];
            float nq = 0.f;
            #pragma unroll
            for (int c=0;c<C_;c++){
                float nv = st[c]*orc[c] + orc[c] + s;
                st[c] = nv; nq += nv*nv;
            }
            float inn = 1.0f/sqrtf(nq);
            #pragma unroll
            for (int c=0;c<C_;c++) st[c] *= inn;
        }
        #pragma unroll
        for (int c=0;c<C_;c++) macc[c] += vrs*st[c] - 0.5f*av[c];
    }
    #pragma unroll
    for (int off2=32; off2; off2>>=1){
        #pragma unroll
        for (int c=0;c<C_;c++) macc[c] += __shfl_xor(macc[c], off2, 64);
    }
    if (lane == 0){
        #pragma unroll
        for (int c=0;c<C_;c++) wacc[wid][c] = macc[c];
    }
    __syncthreads();
    if (!do_head){
        if (tid < C_){
            int c = tid;
            float msum = wacc[0][c]+wacc[1][c]+wacc[2][c]+wacc[3][c];
            float vi = ai[c];
            float vnew = vi + 0.5f*(float)nhit*vi + msum;
            float xn = pi[c] + vnew;
            xout[(size_t)(bb*C_+c)*N_+i] = gelu_f(xn);   // channel-major for next layer
        }
    } else {
        if (tid < C_){
            int c = tid;
            float msum = wacc[0][c]+wacc[1][c]+wacc[2][c]+wacc[3][c];
            float vi = ai[c];
            float vnew = vi + 0.5f*(float)nhit*vi + msum;
            xrow[c] = pi[c] + vnew;                      // layer 3: no gelu
        }
        __syncthreads();
        if (tid < 128){
            float h = fc1b[tid];
            #pragma unroll
            for (int c=0;c<C_;c++) h += xrow[c]*fc1w[c*128+tid];
            float g = gelu_f(h)*fc2w[tid];
            #pragma unroll
            for (int off2=32; off2; off2>>=1) g += __shfl_down(g, off2, 64);
            if (lane==0) psum[wid] = g;
        }
        __syncthreads();
        if (tid==0) out[bb*N_+i] = psum[0] + psum[1] + fc2b[0];
    }
}

extern "C" void kernel_launch(void* const* d_in, const int* in_sizes, int n_in,
                              void* d_out, int out_size, void* d_ws, size_t ws_size,
                              hipStream_t stream) {
    const float* in_x   = (const float*)d_in[0];
    // d_in[1] (v) is dead in the reference forward
    const float* fc0_w  = (const float*)d_in[2];
    const float* fc0_b  = (const float*)d_in[3];
    const float* sc_wr  = (const float*)d_in[4];
    const float* sc_wi  = (const float*)d_in[5];
    const float* w_k    = (const float*)d_in[6];
    const float* w_b    = (const float*)d_in[7];
    const float* fc1_w  = (const float*)d_in[8];
    const float* fc1_b  = (const float*)d_in[9];
    const float* fc2_w  = (const float*)d_in[10];
    const float* fc2_b  = (const float*)d_in[11];
    const float* rv_init= (const float*)d_in[12];
    const float* rv_s   = (const float*)d_in[13];
    float* out = (float*)d_out;
    float* ws  = (float*)d_ws;

    // workspace layout (floats); total 6,716,168 floats = 26.9 MB
    float* rvt   = ws;                 // 6,624,000  [b][pair][20]
    float* x_cur = ws + 6624000;       // 23040      [b][c][n]
    float* p_t   = ws + 6647040;       // 23040      [b][n][20]
    float* a_t   = ws + 6670080;       // 23040      [b][n][20]
    float* Xr    = ws + 6693120;       // 11520
    float* Xi    = ws + 6704640;       // 11520
    float* vmax  = ws + 6716160;       // 8 = [4 layers][2 batches]

    for (int k=0;k<4;k++){
        const size_t woff = (size_t)k*115200;  // 2*20*20*144
        int g_sp = (k==0) ? 44 + TR_SPEC_B : 44;
        int g_iv = (k==0) ? 40 + TR_INV_B  : 40;
        int g_pm = (k==0) ? 2*N_ + TR_PMAX_B : 2*N_;
        k_specp<<<g_sp, 288, 0, stream>>>(x_cur, Xr, Xi, w_k + k*400, w_b + k*20, p_t,
                                          rv_init, rvt, in_x, fc0_w, fc0_b, (k==0) ? 1 : 0,
                                          (unsigned*)vmax);
        k_fft_inv<<<g_iv, 576, 0, stream>>>(Xr, Xi, sc_wr+woff, sc_wi+woff, a_t, rv_init, rvt);
        k_pairmax<<<g_pm, N_, 0, stream>>>(a_t, vmax + 2*k, rv_init, rvt);
        k_vnew<<<2*N_, 256, 0, stream>>>(p_t, a_t, rvt, vmax + 2*k, rv_s, k,
                                         x_cur, (k==3) ? 1 : 0,
                                         fc1_w, fc1_b, fc2_w, fc2_b, out);
    }
}